// Round 1
// baseline (6630.321 us; speedup 1.0000x reference)
//
#include <hip/hip_runtime.h>
#include <hip/hip_bf16.h>
#include <cstdint>

#define TSTEPS 512
#define BATCH  256
#define HID    512
#define INP    64
#define SBg    8            // batch groups (32 rows each)
#define SHs    16           // hidden slices per group (32 cols each)
#define NWG    (SBg*SHs)    // 128 workgroups, 1 wave each
#define BBLK   32
#define HBLK   32
#define KKX    4            // x K-tiles (64/16)
#define KKH    32           // h K-tiles (512/16)

typedef __attribute__((ext_vector_type(8)))  short short8;
typedef __attribute__((ext_vector_type(16))) float f32x16;

// workspace layout
#define HBUF0_OFF 0
#define HBUF1_OFF (BATCH*HID*2)            // 256 KiB each, bf16 h double-buffer
#define HT_OFF    (2*BATCH*HID*2)          // fp32 final h
#define FLAGS_OFF (HT_OFF + BATCH*HID*4)   // per-group per-step arrival counters
#define FLAGS_SZ  (SBg*TSTEPS*4)

__device__ __forceinline__ unsigned short f2bf(float f) {
    unsigned u = __float_as_uint(f);
    return (unsigned short)((u + 0x7FFFu + ((u >> 16) & 1u)) >> 16);  // RNE
}
__device__ __forceinline__ short8 pack8(float4 a0, float4 a1) {
    short8 v;
    v[0]=(short)f2bf(a0.x); v[1]=(short)f2bf(a0.y); v[2]=(short)f2bf(a0.z); v[3]=(short)f2bf(a0.w);
    v[4]=(short)f2bf(a1.x); v[5]=(short)f2bf(a1.y); v[6]=(short)f2bf(a1.z); v[7]=(short)f2bf(a1.w);
    return v;
}
__device__ __forceinline__ float sigm(float x)  { return 1.0f/(1.0f + __expf(-x)); }
__device__ __forceinline__ float tanhf_(float x){ return 2.0f/(1.0f + __expf(-2.0f*x)) - 1.0f; }

__global__ void __launch_bounds__(64, 1)
lstm_persist(const float* __restrict__ x,   const float* __restrict__ Wih,
             const float* __restrict__ Whh, const float* __restrict__ bih,
             const float* __restrict__ bhh, const float* __restrict__ Whead,
             const float* __restrict__ bhead, float* __restrict__ out,
             char* __restrict__ ws)
{
    extern __shared__ short wlds[];   // [KKH][4][64][8] bf16 = 128 KiB, W_hh fragments

    const int lane = threadIdx.x & 63;
    const int g  = blockIdx.x / SHs;  // batch group
    const int hs = blockIdx.x % SHs;  // hidden slice

    unsigned short* hb0 = (unsigned short*)(ws + HBUF0_OFF);
    unsigned short* hb1 = (unsigned short*)(ws + HBUF1_OFF);
    float* hT  = (float*)(ws + HT_OFF);
    int* flags = (int*)(ws + FLAGS_OFF) + g*TSTEPS;

    const int l31 = lane & 31;
    const int khi = (lane >> 5) << 3;   // k sub-block within 16-wide K tile

    // ---- one-time: W_hh slice -> LDS in MFMA B-fragment order ----
    // frag (kk,ty): lane holds W_hh[gc][kk*16 + khi + e], gc = ty*512 + hs*32 + (lane&31)
    for (int fid = 0; fid < KKH*4; ++fid) {
        int kk = fid >> 2, ty = fid & 3;
        int gc = ty*HID + hs*HBLK + l31;
        const float4* s4 = (const float4*)(Whh + (size_t)gc*HID + kk*16 + khi);
        short8 v = pack8(s4[0], s4[1]);
        *((short8*)(wlds + ((fid*64 + lane) << 3))) = v;
    }

    // ---- one-time: W_ih fragments in registers ----
    short8 xb[KKX][4];
    #pragma unroll
    for (int kk = 0; kk < KKX; ++kk)
        #pragma unroll
        for (int ty = 0; ty < 4; ++ty) {
            int gc = ty*HID + hs*HBLK + l31;
            const float4* s4 = (const float4*)(Wih + (size_t)gc*INP + kk*16 + khi);
            xb[kk][ty] = pack8(s4[0], s4[1]);
        }

    float bias_v[4];
    #pragma unroll
    for (int ty = 0; ty < 4; ++ty) {
        int gc = ty*HID + hs*HBLK + l31;
        bias_v[ty] = bih[gc] + bhh[gc];
    }

    __syncthreads();

    f32x16 cst;                       // cell state, fp32, lane-local forever
    #pragma unroll
    for (int e = 0; e < 16; ++e) cst[e] = 0.f;

    const float* xg = x + (size_t)(g*BBLK + l31) * (TSTEPS*INP) + khi;
    const int arow = g*BBLK + l31;
    const int jcol = hs*HBLK + l31;

    #pragma clang loop unroll(disable)
    for (int t = 0; t < TSTEPS; ++t) {
        f32x16 acc[4];
        #pragma unroll
        for (int ty = 0; ty < 4; ++ty)
            #pragma unroll
            for (int e = 0; e < 16; ++e) acc[ty][e] = bias_v[ty];

        // x-projection part first (independent of h_{t-1})
        const float* xt = xg + t*INP;
        #pragma unroll
        for (int kk = 0; kk < KKX; ++kk) {
            const float4* s4 = (const float4*)(xt + kk*16);
            short8 afrag = pack8(s4[0], s4[1]);
            #pragma unroll
            for (int ty = 0; ty < 4; ++ty)
                acc[ty] = __builtin_amdgcn_mfma_f32_32x32x16_bf16(afrag, xb[kk][ty], acc[ty], 0, 0, 0);
        }

        // wait for all 16 producers of h_{t-1}
        if (t > 0) {
            while (__hip_atomic_load(&flags[t-1], __ATOMIC_RELAXED, __HIP_MEMORY_SCOPE_AGENT) < SHs) {}
            __threadfence();   // acquire: invalidate L1/L2 so h reads are fresh
        }

        const unsigned short* hbr = (t & 1) ? hb1 : hb0;
        const unsigned short* ha  = hbr + (size_t)arow*HID + khi;

        // burst-prefetch all 32 A-fragments (pay LLC latency once)
        short8 af[KKH];
        #pragma unroll
        for (int kk = 0; kk < KKH; ++kk)
            af[kk] = *((const short8*)(ha + kk*16));

        #pragma unroll
        for (int kk = 0; kk < KKH; ++kk) {
            #pragma unroll
            for (int ty = 0; ty < 4; ++ty) {
                short8 bf = *((const short8*)(wlds + (((kk*4 + ty)*64 + lane) << 3)));
                acc[ty] = __builtin_amdgcn_mfma_f32_32x32x16_bf16(af[kk], bf, acc[ty], 0, 0, 0);
            }
        }

        // elementwise LSTM update; C layout: col=lane&31, row=(r&3)+8*(r>>2)+4*(lane>>5)
        unsigned short* hbw = (t & 1) ? hb0 : hb1;
        #pragma unroll
        for (int r = 0; r < 16; ++r) {
            float ig = sigm(acc[0][r]);
            float fg = sigm(acc[1][r]);
            float gg = tanhf_(acc[2][r]);
            float og = sigm(acc[3][r]);
            float c  = fg*cst[r] + ig*gg;
            cst[r] = c;
            float h = og*tanhf_(c);
            int brow = g*BBLK + (r & 3) + ((r >> 2) << 3) + ((lane >> 5) << 2);
            hbw[(size_t)brow*HID + jcol] = f2bf(h);
            if (t == TSTEPS-1) hT[(size_t)brow*HID + jcol] = h;
        }

        // release: prior stores globally visible, then arrive
        if (lane == 0)
            __hip_atomic_fetch_add(&flags[t], 1, __ATOMIC_RELEASE, __HIP_MEMORY_SCOPE_AGENT);
    }

    // ---- heads: one WG per batch group computes out[6, 32 rows, 3] ----
    if (hs == 0) {
        while (__hip_atomic_load(&flags[TSTEPS-1], __ATOMIC_RELAXED, __HIP_MEMORY_SCOPE_AGENT) < SHs) {}
        __threadfence();
        for (int idx = lane; idx < 6*BBLK*3; idx += 64) {
            int k  = idx / (BBLK*3);
            int rb = idx % (BBLK*3);
            int bl = rb / 3, o = rb % 3;
            int b  = g*BBLK + bl;
            const float* hp = hT + (size_t)b*HID;
            const float* wp = Whead + (size_t)(k*3 + o)*HID;
            float s = 0.f;
            for (int hh = 0; hh < HID; hh += 4) {
                float4 hv = *(const float4*)(hp + hh);
                float4 wv = *(const float4*)(wp + hh);
                s += hv.x*wv.x + hv.y*wv.y + hv.z*wv.z + hv.w*wv.w;
            }
            out[(k*BATCH + b)*3 + o] = s + bhead[k*3 + o];
        }
    }
}

extern "C" void kernel_launch(void* const* d_in, const int* in_sizes, int n_in,
                              void* d_out, int out_size, void* d_ws, size_t ws_size,
                              hipStream_t stream) {
    (void)in_sizes; (void)n_in; (void)out_size; (void)ws_size;
    const float* x     = (const float*)d_in[0];
    const float* Wih   = (const float*)d_in[1];
    const float* Whh   = (const float*)d_in[2];
    const float* bih   = (const float*)d_in[3];
    const float* bhh   = (const float*)d_in[4];
    const float* Whead = (const float*)d_in[5];
    const float* bhead = (const float*)d_in[6];
    char* ws = (char*)d_ws;

    // allow 128 KiB dynamic LDS (idempotent host-side call, not captured)
    (void)hipFuncSetAttribute((const void*)lstm_persist,
                              hipFuncAttributeMaxDynamicSharedMemorySize, 131072);

    // reset: h_0 = 0 and per-step flags = 0 (ws is not re-poisoned between replays)
    (void)hipMemsetAsync(ws + HBUF0_OFF, 0, BATCH*HID*2, stream);
    (void)hipMemsetAsync(ws + FLAGS_OFF, 0, FLAGS_SZ, stream);

    hipLaunchKernelGGL(lstm_persist, dim3(NWG), dim3(64), 131072, stream,
                       x, Wih, Whh, bih, bhh, Whead, bhead, (float*)d_out, ws);
}

// Round 3
// 1642.771 us; speedup vs baseline: 4.0361x; 4.0361x over previous
//
#include <hip/hip_runtime.h>
#include <hip/hip_bf16.h>
#include <cstdint>

#define TSTEPS 512
#define BATCH  256
#define HID    512
#define INP    64
#define NGRP   16          // batch groups
#define GROWS  16          // batch rows per group
#define NSL    16          // WG slices per group (32 hid cols each)
#define NWG    256
#define KTH    16          // h K-tiles (512/32)
#define KTX    2           // x K-tiles (64/32)

typedef __attribute__((ext_vector_type(8))) short short8;
typedef __attribute__((ext_vector_type(4))) float f32x4;
typedef __attribute__((ext_vector_type(2))) unsigned long long ull2;

// workspace layout
#define HB0_OFF   0
#define HB1_OFF   (BATCH*HID*2)
#define HT_OFF    (2*BATCH*HID*2)
#define FLAGS_OFF (HT_OFF + BATCH*HID*4)
#define CNT_OFF   (FLAGS_OFF + NGRP*TSTEPS*4)
#define ZERO2_SZ  (NGRP*TSTEPS*4 + 64)

__device__ __forceinline__ unsigned short f2bf(float f) {
    unsigned u = __float_as_uint(f);
    return (unsigned short)((u + 0x7FFFu + ((u >> 16) & 1u)) >> 16);  // RNE
}
__device__ __forceinline__ short8 pack8(float4 a0, float4 a1) {
    short8 v;
    v[0]=(short)f2bf(a0.x); v[1]=(short)f2bf(a0.y); v[2]=(short)f2bf(a0.z); v[3]=(short)f2bf(a0.w);
    v[4]=(short)f2bf(a1.x); v[5]=(short)f2bf(a1.y); v[6]=(short)f2bf(a1.z); v[7]=(short)f2bf(a1.w);
    return v;
}
__device__ __forceinline__ float sigm(float x)  { return 1.0f/(1.0f + __expf(-x)); }
__device__ __forceinline__ float tanhf_(float x){ return 2.0f/(1.0f + __expf(-2.0f*x)) - 1.0f; }

__global__ void __launch_bounds__(256, 1)
lstm_persist(const float* __restrict__ x,   const float* __restrict__ Wih,
             const float* __restrict__ Whh, const float* __restrict__ bih,
             const float* __restrict__ bhh, const float* __restrict__ Whead,
             const float* __restrict__ bhead, float* __restrict__ out,
             char* __restrict__ ws)
{
    extern __shared__ char lds[];   // 128 KiB requested (forces 1 WG/CU); ~32 KiB used
    const int tid  = threadIdx.x;
    const int lane = tid & 63;
    const int wv   = tid >> 6;
    const int l15  = lane & 15, lq = lane >> 4, l7 = lane & 7;

    unsigned short* hb0 = (unsigned short*)(ws + HB0_OFF);
    unsigned short* hb1 = (unsigned short*)(ws + HB1_OFF);
    float* hT  = (float*)(ws + HT_OFF);
    int* flags = (int*)(ws + FLAGS_OFF);
    int* cnt   = (int*)(ws + CNT_OFF);

    // ---- self-organize by XCD: 32 WGs/XCD (capacity-guaranteed) -> 2 groups x 16 slices ----
    int* org = (int*)(lds + 131056);   // tail of dynamic LDS, untouched elsewhere
    if (tid == 0) {
        unsigned xcd;
        asm volatile("s_getreg_b32 %0, hwreg(HW_REG_XCC_ID)" : "=s"(xcd));
        xcd &= 7u;
        int slot = __hip_atomic_fetch_add(&cnt[xcd], 1, __ATOMIC_RELAXED, __HIP_MEMORY_SCOPE_AGENT) & 31;
        org[0] = (int)xcd * 2 + (slot >> 4);
        org[1] = slot & 15;
    }
    __syncthreads();
    const int g  = org[0];
    const int sl = org[1];
    const int hbase = sl*32 + wv*8;        // wave's hidden-col base
    const int gsel  = l15 >> 3;            // gate select within N-tile

    // ---- W_hh fragments resident in VGPRs: 16 Ktiles x 2 Ntiles x 4 VGPR = 128 ----
    // Ntile0 cols = [gate i: hid 0..7 | gate f: hid 0..7]; Ntile1 = [g | o]
    short8 whh[KTH][2];
    #pragma unroll
    for (int kt = 0; kt < KTH; ++kt)
        #pragma unroll
        for (int nt = 0; nt < 2; ++nt) {
            int grow = (nt*2 + gsel)*HID + hbase + l7;
            const float4* p = (const float4*)(Whh + (size_t)grow*HID + kt*32 + lq*8);
            whh[kt][nt] = pack8(p[0], p[1]);
        }
    short8 wihf[KTX][2];
    #pragma unroll
    for (int kt = 0; kt < KTX; ++kt)
        #pragma unroll
        for (int nt = 0; nt < 2; ++nt) {
            int grow = (nt*2 + gsel)*HID + hbase + l7;
            const float4* p = (const float4*)(Wih + (size_t)grow*INP + kt*32 + lq*8);
            wihf[kt][nt] = pack8(p[0], p[1]);
        }
    float bias0, bias1;
    { int gr = (0*2 + gsel)*HID + hbase + l7; bias0 = bih[gr] + bhh[gr]; }
    { int gr = (1*2 + gsel)*HID + hbase + l7; bias1 = bih[gr] + bhh[gr]; }

    unsigned short* hg0 = hb0 + (size_t)g*GROWS*HID;
    unsigned short* hg1 = hb1 + (size_t)g*GROWS*HID;
    float*          hTg = hT  + (size_t)g*GROWS*HID;
    const int frow = g*TSTEPS;

    // staging map: thread -> (ktile = tid>>4, row = tid&15), 64B contiguous global chunk
    const int skt = tid >> 4, sr = tid & 15;
    char* swp = lds + skt*1024 + sr*16;            // + s*256 for k-sub-block s=0..3
    const char* srp = lds + lane*16;               // frag read: + kt*1024  (conflict-free)

    const float* xrow = x + ((size_t)(g*GROWS + l15)*TSTEPS)*INP + lq*8;

    f32x4 cst = {0.f, 0.f, 0.f, 0.f};

    // x prefetch for t=0
    float4 xv0 = *(const float4*)(xrow);
    float4 xv1 = *(const float4*)(xrow + 4);
    float4 xv2 = *(const float4*)(xrow + 32);
    float4 xv3 = *(const float4*)(xrow + 36);

    #pragma clang loop unroll(disable)
    for (int t = 0; t < TSTEPS; ++t) {
        f32x4 acc0 = {bias0, bias0, bias0, bias0};
        f32x4 acc1 = {bias1, bias1, bias1, bias1};

        // x-projection (independent of h_{t-1}) from prefetched regs
        {
            short8 af0 = pack8(xv0, xv1);
            short8 af1 = pack8(xv2, xv3);
            acc0 = __builtin_amdgcn_mfma_f32_16x16x32_bf16(af0, wihf[0][0], acc0, 0, 0, 0);
            acc1 = __builtin_amdgcn_mfma_f32_16x16x32_bf16(af0, wihf[0][1], acc1, 0, 0, 0);
            acc0 = __builtin_amdgcn_mfma_f32_16x16x32_bf16(af1, wihf[1][0], acc0, 0, 0, 0);
            acc1 = __builtin_amdgcn_mfma_f32_16x16x32_bf16(af1, wihf[1][1], acc1, 0, 0, 0);
        }
        __builtin_amdgcn_sched_barrier(0);   // keep x-part above the spin

        if (t) {
            const int* fl = flags + frow + (t-1);
            while (__hip_atomic_load(fl, __ATOMIC_RELAXED, __HIP_MEMORY_SCOPE_AGENT) < NSL) {}
            asm volatile("" ::: "memory");
        }

        // stage h_{t-1} tile (16x512 bf16) into LDS in A-fragment order.
        // 8-byte RELAXED/AGENT atomic loads: guaranteed L1-bypass (the R2 bug),
        // no fences -> h stays resident in this XCD's L2.
        {
            const unsigned long long* gq = (const unsigned long long*)
                ((const char*)((t & 1) ? hg1 : hg0) + sr*1024 + skt*64);
            unsigned long long hv[8];
            #pragma unroll
            for (int j = 0; j < 8; ++j)
                hv[j] = __hip_atomic_load(gq + j, __ATOMIC_RELAXED, __HIP_MEMORY_SCOPE_AGENT);
            #pragma unroll
            for (int s = 0; s < 4; ++s) {
                ull2 w; w[0] = hv[2*s]; w[1] = hv[2*s+1];
                *(ull2*)(swp + s*256) = w;
            }
        }
        __syncthreads();

        // x prefetch for t+1 (hidden under MFMA + epilogue)
        if (t + 1 < TSTEPS) {
            const float* xn = xrow + (size_t)(t+1)*INP;
            xv0 = *(const float4*)(xn);
            xv1 = *(const float4*)(xn + 4);
            xv2 = *(const float4*)(xn + 32);
            xv3 = *(const float4*)(xn + 36);
        }

        #pragma unroll
        for (int kt = 0; kt < KTH; ++kt) {
            short8 a = *(const short8*)(srp + kt*1024);
            acc0 = __builtin_amdgcn_mfma_f32_16x16x32_bf16(a, whh[kt][0], acc0, 0, 0, 0);
            acc1 = __builtin_amdgcn_mfma_f32_16x16x32_bf16(a, whh[kt][1], acc1, 0, 0, 0);
        }

        // epilogue: C layout col=lane&15, row=(lane>>4)*4+r
        unsigned short* hbw = (t & 1) ? hg0 : hg1;
        #pragma unroll
        for (int r = 0; r < 4; ++r) {
            float a0 = acc0[r], a1 = acc1[r];
            float s0 = __shfl_xor(a0, 8);
            float s1 = __shfl_xor(a1, 8);
            bool lo = (l15 < 8);
            float iv = lo ? a0 : s0;
            float fv = lo ? s0 : a0;
            float gv = lo ? a1 : s1;
            float ov = lo ? s1 : a1;
            float c  = sigm(fv)*cst[r] + sigm(iv)*tanhf_(gv);
            cst[r] = c;
            float h  = sigm(ov)*tanhf_(c);
            if (lo) {
                int idx = (lq*4 + r)*HID + hbase + l7;
                hbw[idx] = f2bf(h);
                if (t == TSTEPS-1) hTg[idx] = h;
            }
        }
        __syncthreads();   // drains each wave's vmcnt -> all stores visible in this XCD's L2
        if (tid == 0)
            __hip_atomic_fetch_add(&flags[frow + t], 1, __ATOMIC_RELAXED, __HIP_MEMORY_SCOPE_AGENT);
    }

    // ---- heads: slice-0 WG of each group ----
    if (sl == 0) {
        const int* fl = flags + frow + (TSTEPS-1);
        while (__hip_atomic_load(fl, __ATOMIC_RELAXED, __HIP_MEMORY_SCOPE_AGENT) < NSL) {}
        asm volatile("" ::: "memory");
        // stage hT tile (16x512 f32 = 32 KiB) into LDS; these addresses were never
        // read before by this WG (no stale-L1 path) -> plain loads are safe.
        {
            const float4* gp = (const float4*)((const char*)hTg + tid*128);
            float4* wp = (float4*)(lds + tid*128);
            #pragma unroll
            for (int j = 0; j < 8; ++j) wp[j] = gp[j];
        }
        __syncthreads();
        const float* hsm = (const float*)lds;
        for (int idx = tid; idx < 6*GROWS*3; idx += 256) {
            int k = idx / (GROWS*3), rem = idx % (GROWS*3);
            int row = rem / 3, o = rem % 3;
            const float* wp = Whead + ((size_t)k*3 + o)*HID;
            const float* hp = hsm + row*HID;
            float s = 0.f;
            for (int hh = 0; hh < HID; hh += 4) {
                float4 hv = *(const float4*)(hp + hh);
                float4 wv = *(const float4*)(wp + hh);
                s += hv.x*wv.x + hv.y*wv.y + hv.z*wv.z + hv.w*wv.w;
            }
            out[((size_t)k*BATCH + g*GROWS + row)*3 + o] = s + bhead[k*3 + o];
        }
    }
}

extern "C" void kernel_launch(void* const* d_in, const int* in_sizes, int n_in,
                              void* d_out, int out_size, void* d_ws, size_t ws_size,
                              hipStream_t stream) {
    (void)in_sizes; (void)n_in; (void)out_size; (void)ws_size;
    const float* x     = (const float*)d_in[0];
    const float* Wih   = (const float*)d_in[1];
    const float* Whh   = (const float*)d_in[2];
    const float* bih   = (const float*)d_in[3];
    const float* bhh   = (const float*)d_in[4];
    const float* Whead = (const float*)d_in[5];
    const float* bhead = (const float*)d_in[6];
    char* ws = (char*)d_ws;

    (void)hipFuncSetAttribute((const void*)lstm_persist,
                              hipFuncAttributeMaxDynamicSharedMemorySize, 131072);

    // per-launch reset: h_0 = 0, flags = 0, xcd slot counters = 0
    (void)hipMemsetAsync(ws + HB0_OFF, 0, BATCH*HID*2, stream);
    (void)hipMemsetAsync(ws + FLAGS_OFF, 0, ZERO2_SZ, stream);

    hipLaunchKernelGGL(lstm_persist, dim3(NWG), dim3(256), 131072, stream,
                       x, Wih, Whh, bih, bhh, Whead, bhead, (float*)d_out, ws);
}